// Round 1
// baseline (19753.513 us; speedup 1.0000x reference)
//
#include <hip/hip_runtime.h>
#include <math.h>

// Problem constants
#define S_ 512
#define B_ 64
#define E_ 512
#define H_ 1024
#define Z_ 4096

typedef _Float16 half8 __attribute__((ext_vector_type(8)));
typedef float f32x4 __attribute__((ext_vector_type(4)));

// ---------------- workspace layout (bytes) ----------------
constexpr size_t SZ_IMG1 = (size_t)128 * 2 * 48 * 64 * 8 * 2; // 12,582,912
constexpr size_t SZ_IMG2 = (size_t)128 * 2 * 64 * 64 * 8 * 2; // 16,777,216
constexpr size_t SZ_X1   = (size_t)S_ * B_ * E_ * 2;          // 33,554,432
constexpr size_t SZ_HB   = (size_t)2 * B_ * H_ * 2;           // 262,144
constexpr size_t SZ_ST   = (size_t)4 * B_ * 2 * 4;            // 2,048

constexpr size_t OFF_IMG1 = 0;
constexpr size_t OFF_IMG2 = OFF_IMG1 + SZ_IMG1;
constexpr size_t OFF_X1   = OFF_IMG2 + SZ_IMG2;
constexpr size_t OFF_H1   = OFF_X1 + SZ_X1;
constexpr size_t OFF_H2   = OFF_H1 + SZ_HB;
constexpr size_t OFF_S1   = OFF_H2 + SZ_HB;
constexpr size_t OFF_S2   = OFF_S1 + SZ_ST;
constexpr size_t OFF_GW   = OFF_S2 + SZ_ST;
constexpr size_t OFF_B2E  = OFF_GW + (size_t)Z_ * 4;
constexpr size_t OFF_SYNC = OFF_B2E + (size_t)Z_ * 4;
constexpr size_t OFF_END  = OFF_SYNC + 2048;

// dynamic LDS: [0,131072) weights, [131072, +8448) z tile, then 2*64 floats stats
constexpr int LDS_Z_OFF  = 131072;
constexpr int LDS_SL_OFF = 131072 + 8448;
constexpr int LDS_TOTAL  = LDS_SL_OFF + 512; // 140,032

// ---------------- setup kernels ----------------

__global__ void k_zero_ws(float* __restrict__ p, unsigned n) {
    unsigned i = blockIdx.x * 256u + threadIdx.x;
    if (i < n) p[i] = 0.f;
}

// gather emb rows into fp16 x1seq[(t*64+b)][k]
__global__ void k_gather(const int* __restrict__ src, const float* __restrict__ emb,
                         _Float16* __restrict__ x1) {
    int u = blockIdx.x * 256 + threadIdx.x;        // 2,097,152 units of 8 elems
    int k = (u & 63) * 8;
    int rowi = u >> 6;                              // s*64 + b
    int s = rowi >> 6, b = rowi & 63;
    int tok = src[b * S_ + s];
    const float4* ep = (const float4*)(emb + (size_t)tok * E_ + k);
    float4 v0 = ep[0], v1 = ep[1];
    half8 o;
    o[0] = (_Float16)v0.x; o[1] = (_Float16)v0.y; o[2] = (_Float16)v0.z; o[3] = (_Float16)v0.w;
    o[4] = (_Float16)v1.x; o[5] = (_Float16)v1.y; o[6] = (_Float16)v1.z; o[7] = (_Float16)v1.w;
    *(half8*)(x1 + (size_t)rowi * E_ + k) = o;
}

// swizzle weights into MFMA B-fragment order, fp16.
// img1[bk][nt][ch(48)][lane][j]: k = ch*32 + (lane>>4)*8 + j ; k<512 -> Wx1, else Wh1
// img2[bk][nt][ch(64)][lane][j]: k<1024 -> Wx2*g_ln1[k], else Wh2
__global__ void k_swz(const float* __restrict__ Wx1, const float* __restrict__ Wh1,
                      const float* __restrict__ Wx2, const float* __restrict__ Wh2,
                      const float* __restrict__ gln1,
                      _Float16* __restrict__ img1, _Float16* __restrict__ img2) {
    int u = blockIdx.x * 256 + threadIdx.x;
    const int U1 = 128 * 2 * 48 * 64;
    if (u < U1) {
        int lane = u & 63; int r = u >> 6;
        int ch = r % 48; r /= 48;
        int nt = r & 1; int bk = r >> 1;
        int n = nt * 16 + (lane & 15);
        int zcol = (n >> 3) * 1024 + bk * 8 + (n & 7);
        int kb = ch * 32 + ((lane >> 4) * 8);
        half8 o;
#pragma unroll
        for (int j = 0; j < 8; ++j) {
            int k = kb + j;
            float v = (k < E_) ? Wx1[(size_t)k * Z_ + zcol] : Wh1[(size_t)(k - E_) * Z_ + zcol];
            o[j] = (_Float16)v;
        }
        *(half8*)(img1 + (size_t)u * 8) = o;
    } else {
        int u2 = u - U1;
        if (u2 >= 128 * 2 * 64 * 64) return;
        int lane = u2 & 63; int r = u2 >> 6;
        int ch = r % 64; r /= 64;
        int nt = r & 1; int bk = r >> 1;
        int n = nt * 16 + (lane & 15);
        int zcol = (n >> 3) * 1024 + bk * 8 + (n & 7);
        int kb = ch * 32 + ((lane >> 4) * 8);
        half8 o;
#pragma unroll
        for (int j = 0; j < 8; ++j) {
            int k = kb + j;
            float v = (k < H_) ? Wx2[(size_t)k * Z_ + zcol] * gln1[k]
                               : Wh2[(size_t)(k - H_) * Z_ + zcol];
            o[j] = (_Float16)v;
        }
        *(half8*)(img2 + (size_t)u2 * 8) = o;
    }
}

// column sums: Gw[c] = sum_k g_ln1[k]*Wx2[k][c]; B2e[c] = b2[c] + sum_k b_ln1[k]*Wx2[k][c]
__global__ void k_colsum(const float* __restrict__ Wx2, const float* __restrict__ gln1,
                         const float* __restrict__ bln1, const float* __restrict__ b2,
                         float* __restrict__ Gw, float* __restrict__ B2e) {
    int c = blockIdx.x * 256 + threadIdx.x;
    if (c >= Z_) return;
    float ag = 0.f, ab = 0.f;
    for (int k = 0; k < H_; ++k) {
        float w = Wx2[(size_t)k * Z_ + c];
        ag += gln1[k] * w;
        ab += bln1[k] * w;
    }
    Gw[c] = ag;
    B2e[c] = b2[c] + ab;
}

// ---------------- persistent recurrent kernel ----------------

__device__ __forceinline__ float sigm_(float x) { return 1.f / (1.f + __expf(-x)); }
__device__ __forceinline__ float tanh_(float x) { return 1.f - 2.f / (__expf(2.f * x) + 1.f); }

__global__ void __launch_bounds__(256, 1)
k_rnn(const float* __restrict__ b1,
      const float* __restrict__ gln2, const float* __restrict__ bln2,
      const _Float16* __restrict__ img1, const _Float16* __restrict__ img2,
      const _Float16* __restrict__ x1seq,
      _Float16* __restrict__ h1buf, _Float16* __restrict__ h2buf,
      float* __restrict__ s1, float* __restrict__ s2,
      const float* __restrict__ Gw, const float* __restrict__ B2e,
      unsigned int* __restrict__ gsync,
      float* __restrict__ out) {
    extern __shared__ char smem[];
    float* zl = (float*)(smem + LDS_Z_OFF);          // [64][33] padded
    float* sl_mean = (float*)(smem + LDS_SL_OFF);    // [64]
    float* sl_inv = sl_mean + 64;                    // [64]

    const int tid = threadIdx.x;
    const int bid = blockIdx.x;
    const bool is2 = bid >= 128;
    const int bk = is2 ? bid - 128 : bid;
    const int wv = tid >> 6, lane = tid & 63;
    const int quad = lane >> 4, m15 = lane & 15;
    const int hc = tid & 7;
    const int b0 = tid >> 3;          // 0..31
    const int col = bk * 8 + hc;
    const int row = wv * 16 + m15;    // A-operand batch row

    // stage pre-swizzled weights into LDS
    {
        const uint4* s = (const uint4*)(is2 ? (img2 + (size_t)bk * (2 * 64 * 64 * 8))
                                            : (img1 + (size_t)bk * (2 * 48 * 64 * 8)));
        uint4* d = (uint4*)smem;
        int n16 = is2 ? (131072 / 16) : (98304 / 16);
        for (int i = tid; i < n16; i += 256) d[i] = s[i];
    }

    float bias[4], gl2v = 0.f, bl2v = 0.f, gw0 = 0.f, gw1 = 0.f;
    if (!is2) {
#pragma unroll
        for (int g = 0; g < 4; ++g) bias[g] = b1[g * 1024 + col];
    } else {
#pragma unroll
        for (int g = 0; g < 4; ++g) bias[g] = B2e[g * 1024 + col];
        gl2v = gln2[col]; bl2v = bln2[col];
        int na = m15, nb = 16 + m15;
        gw0 = Gw[(na >> 3) * 1024 + bk * 8 + (na & 7)];
        gw1 = Gw[(nb >> 3) * 1024 + bk * 8 + (nb & 7)];
    }
    float c_own[2] = {0.f, 0.f}, h_own[2] = {0.f, 0.f};

    __syncthreads();
    const half8* wb = (const half8*)smem;

    for (int t = 0; t <= S_ + 1; ++t) {
        if (!is2) {
            // ---------------- layer-1 cell, step t ----------------
            if (t < S_) {
                f32x4 a0 = {0.f, 0.f, 0.f, 0.f}, a1 = {0.f, 0.f, 0.f, 0.f};
                const half8* xp = (const half8*)(x1seq + (size_t)(t * 64 + row) * E_ + quad * 8);
#pragma unroll 4
                for (int ch = 0; ch < 16; ++ch) {
                    half8 a = xp[ch * 4];
                    a0 = __builtin_amdgcn_mfma_f32_16x16x32_f16(a, wb[(0 * 48 + ch) * 64 + lane], a0, 0, 0, 0);
                    a1 = __builtin_amdgcn_mfma_f32_16x16x32_f16(a, wb[(1 * 48 + ch) * 64 + lane], a1, 0, 0, 0);
                }
                const half8* hp = (const half8*)(h1buf + (size_t)((t + 1) & 1) * (B_ * H_) + (size_t)row * H_ + quad * 8);
#pragma unroll 4
                for (int ch = 0; ch < 32; ++ch) {
                    half8 a = hp[ch * 4];
                    a0 = __builtin_amdgcn_mfma_f32_16x16x32_f16(a, wb[(0 * 48 + 16 + ch) * 64 + lane], a0, 0, 0, 0);
                    a1 = __builtin_amdgcn_mfma_f32_16x16x32_f16(a, wb[(1 * 48 + 16 + ch) * 64 + lane], a1, 0, 0, 0);
                }
#pragma unroll
                for (int r = 0; r < 4; ++r) {
                    int orow = wv * 16 + quad * 4 + r;
                    zl[orow * 33 + m15] = a0[r];
                    zl[orow * 33 + 16 + m15] = a1[r];
                }
                __syncthreads();
#pragma unroll
                for (int p = 0; p < 2; ++p) {
                    int b = b0 + 32 * p;
                    float iv = zl[b * 33 + hc] + bias[0];
                    float fv = zl[b * 33 + 8 + hc] + bias[1];
                    float ov = zl[b * 33 + 16 + hc] + bias[2];
                    float gv = zl[b * 33 + 24 + hc] + bias[3];
                    float c = sigm_(fv) * c_own[p] + sigm_(iv) * tanh_(gv);
                    float h = sigm_(ov) * tanh_(c);
                    c_own[p] = c; h_own[p] = h;
                    h1buf[(size_t)(t & 1) * (B_ * H_) + (size_t)b * H_ + col] = (_Float16)h;
                    float sm = h, sq = h * h;
                    sm += __shfl_xor(sm, 1); sm += __shfl_xor(sm, 2); sm += __shfl_xor(sm, 4);
                    sq += __shfl_xor(sq, 1); sq += __shfl_xor(sq, 2); sq += __shfl_xor(sq, 4);
                    if (hc == 0) {
                        atomicAdd(&s1[(size_t)(t & 3) * 128 + b * 2 + 0], sm);
                        atomicAdd(&s1[(size_t)(t & 3) * 128 + b * 2 + 1], sq);
                    }
                }
            }
            if (tid == 0 && bk < 64) { // zero stats slot to be written next phase
                s1[(size_t)((t + 1) & 3) * 128 + bk * 2 + 0] = 0.f;
                s1[(size_t)((t + 1) & 3) * 128 + bk * 2 + 1] = 0.f;
            }
        } else {
            // ---------------- layer-2 cell, step t-1 (+ output LN of step t-2) ----------------
            if (t >= 2) {
                int to = t - 2;
#pragma unroll
                for (int p = 0; p < 2; ++p) {
                    int b = b0 + 32 * p;
                    float sm = s2[(size_t)(to & 3) * 128 + b * 2 + 0];
                    float sq = s2[(size_t)(to & 3) * 128 + b * 2 + 1];
                    float mean = sm * (1.f / 1024.f);
                    float inv = rsqrtf(sq * (1.f / 1024.f) - mean * mean + 1e-5f);
                    out[(size_t)b * (S_ * H_) + (size_t)to * H_ + col] =
                        (h_own[p] - mean) * inv * gl2v + bl2v;
                }
            }
            if (t >= 1 && t <= S_) {
                int tt = t - 1;
                if (tid < 64) {
                    float sm = s1[(size_t)(tt & 3) * 128 + tid * 2 + 0];
                    float sq = s1[(size_t)(tt & 3) * 128 + tid * 2 + 1];
                    float mean = sm * (1.f / 1024.f);
                    sl_mean[tid] = mean;
                    sl_inv[tid] = rsqrtf(sq * (1.f / 1024.f) - mean * mean + 1e-5f);
                }
                f32x4 ax0 = {0.f, 0.f, 0.f, 0.f}, ax1 = {0.f, 0.f, 0.f, 0.f};
                f32x4 ah0 = {0.f, 0.f, 0.f, 0.f}, ah1 = {0.f, 0.f, 0.f, 0.f};
                const half8* hp1 = (const half8*)(h1buf + (size_t)(tt & 1) * (B_ * H_) + (size_t)row * H_ + quad * 8);
#pragma unroll 4
                for (int ch = 0; ch < 32; ++ch) {
                    half8 a = hp1[ch * 4];
                    ax0 = __builtin_amdgcn_mfma_f32_16x16x32_f16(a, wb[(0 * 64 + ch) * 64 + lane], ax0, 0, 0, 0);
                    ax1 = __builtin_amdgcn_mfma_f32_16x16x32_f16(a, wb[(1 * 64 + ch) * 64 + lane], ax1, 0, 0, 0);
                }
                const half8* hp2 = (const half8*)(h2buf + (size_t)(t & 1) * (B_ * H_) + (size_t)row * H_ + quad * 8);
#pragma unroll 4
                for (int ch = 0; ch < 32; ++ch) {
                    half8 a = hp2[ch * 4];
                    ah0 = __builtin_amdgcn_mfma_f32_16x16x32_f16(a, wb[(0 * 64 + 32 + ch) * 64 + lane], ah0, 0, 0, 0);
                    ah1 = __builtin_amdgcn_mfma_f32_16x16x32_f16(a, wb[(1 * 64 + 32 + ch) * 64 + lane], ah1, 0, 0, 0);
                }
                __syncthreads(); // sl ready; zl free
#pragma unroll
                for (int r = 0; r < 4; ++r) {
                    int orow = wv * 16 + quad * 4 + r;
                    float m = sl_mean[orow], iv = sl_inv[orow];
                    zl[orow * 33 + m15] = (ax0[r] - m * gw0) * iv + ah0[r];
                    zl[orow * 33 + 16 + m15] = (ax1[r] - m * gw1) * iv + ah1[r];
                }
                __syncthreads();
#pragma unroll
                for (int p = 0; p < 2; ++p) {
                    int b = b0 + 32 * p;
                    float iv = zl[b * 33 + hc] + bias[0];
                    float fv = zl[b * 33 + 8 + hc] + bias[1];
                    float ov = zl[b * 33 + 16 + hc] + bias[2];
                    float gv = zl[b * 33 + 24 + hc] + bias[3];
                    float c = sigm_(fv) * c_own[p] + sigm_(iv) * tanh_(gv);
                    float h = sigm_(ov) * tanh_(c);
                    c_own[p] = c; h_own[p] = h;
                    h2buf[(size_t)(tt & 1) * (B_ * H_) + (size_t)b * H_ + col] = (_Float16)h;
                    float sm = h, sq = h * h;
                    sm += __shfl_xor(sm, 1); sm += __shfl_xor(sm, 2); sm += __shfl_xor(sm, 4);
                    sq += __shfl_xor(sq, 1); sq += __shfl_xor(sq, 2); sq += __shfl_xor(sq, 4);
                    if (hc == 0) {
                        atomicAdd(&s2[(size_t)(tt & 3) * 128 + b * 2 + 0], sm);
                        atomicAdd(&s2[(size_t)(tt & 3) * 128 + b * 2 + 1], sq);
                    }
                }
            }
            if (tid == 0 && bk < 64) {
                s2[(size_t)(t & 3) * 128 + bk * 2 + 0] = 0.f;
                s2[(size_t)(t & 3) * 128 + bk * 2 + 1] = 0.f;
            }
        }

        // ---------------- grid barrier (two-level) ----------------
        if (t <= S_) {
            __syncthreads();
            if (tid == 0) {
                __threadfence();
                int grp = bid & 7;
                unsigned old = __hip_atomic_fetch_add(&gsync[32 * (grp + 1)], 1u,
                                                      __ATOMIC_RELEASE, __HIP_MEMORY_SCOPE_AGENT);
                if (old == 32u * (unsigned)(t + 1) - 1u) {
                    __hip_atomic_fetch_add(&gsync[0], 1u, __ATOMIC_RELEASE, __HIP_MEMORY_SCOPE_AGENT);
                }
                unsigned tgt = 8u * (unsigned)(t + 1);
                while (__hip_atomic_load(&gsync[0], __ATOMIC_ACQUIRE, __HIP_MEMORY_SCOPE_AGENT) < tgt) {
                    __builtin_amdgcn_s_sleep(2);
                }
            }
            __syncthreads();
        }
    }

    // ---------------- finals ----------------
    const size_t BASE_H = (size_t)B_ * S_ * H_;
    const size_t BASE_C = BASE_H + (size_t)B_ * 2 * H_;
    int cc = is2 ? (1024 + col) : col;
#pragma unroll
    for (int p = 0; p < 2; ++p) {
        int b = b0 + 32 * p;
        out[BASE_H + (size_t)b * 2048 + cc] = h_own[p];
        out[BASE_C + (size_t)b * 2048 + cc] = c_own[p];
    }
}

// ---------------- host ----------------

extern "C" void kernel_launch(void* const* d_in, const int* in_sizes, int n_in,
                              void* d_out, int out_size, void* d_ws, size_t ws_size,
                              hipStream_t stream) {
    const int* src = (const int*)d_in[0];
    const float* emb = (const float*)d_in[1];
    const float* Wx1 = (const float*)d_in[2];
    const float* Wh1 = (const float*)d_in[3];
    const float* b1 = (const float*)d_in[4];
    const float* Wx2 = (const float*)d_in[5];
    const float* Wh2 = (const float*)d_in[6];
    const float* b2 = (const float*)d_in[7];
    const float* gl1 = (const float*)d_in[8];
    const float* bl1 = (const float*)d_in[9];
    const float* gl2 = (const float*)d_in[10];
    const float* bl2 = (const float*)d_in[11];
    float* out = (float*)d_out;
    char* ws = (char*)d_ws;
    if (ws_size < OFF_END) return;

    _Float16* img1 = (_Float16*)(ws + OFF_IMG1);
    _Float16* img2 = (_Float16*)(ws + OFF_IMG2);
    _Float16* x1seq = (_Float16*)(ws + OFF_X1);
    _Float16* h1buf = (_Float16*)(ws + OFF_H1);
    _Float16* h2buf = (_Float16*)(ws + OFF_H2);
    float* s1 = (float*)(ws + OFF_S1);
    float* s2 = (float*)(ws + OFF_S2);
    float* Gw = (float*)(ws + OFF_GW);
    float* B2e = (float*)(ws + OFF_B2E);
    unsigned int* gsync = (unsigned int*)(ws + OFF_SYNC);

    (void)hipFuncSetAttribute((const void*)k_rnn,
                              hipFuncAttributeMaxDynamicSharedMemorySize, LDS_TOTAL);

    unsigned zero_n = (unsigned)((OFF_END - OFF_H1) / 4);
    k_zero_ws<<<(zero_n + 255) / 256, 256, 0, stream>>>((float*)(ws + OFF_H1), zero_n);
    k_gather<<<8192, 256, 0, stream>>>(src, emb, x1seq);
    k_swz<<<7168, 256, 0, stream>>>(Wx1, Wh1, Wx2, Wh2, gl1, img1, img2);
    k_colsum<<<16, 256, 0, stream>>>(Wx2, gl1, bl1, b2, Gw, B2e);
    k_rnn<<<256, 256, LDS_TOTAL, stream>>>(b1, gl2, bl2, img1, img2, x1seq,
                                           h1buf, h2buf, s1, s2, Gw, B2e, gsync, out);
}

// Round 2
// 14326.364 us; speedup vs baseline: 1.3788x; 1.3788x over previous
//
#include <hip/hip_runtime.h>
#include <math.h>

// Problem constants
#define S_ 512
#define B_ 64
#define E_ 512
#define H_ 1024
#define Z_ 4096

typedef _Float16 half8 __attribute__((ext_vector_type(8)));
typedef float f32x4 __attribute__((ext_vector_type(4)));

// ---------------- workspace layout (bytes) ----------------
constexpr size_t SZ_IMG1 = (size_t)128 * 2 * 48 * 64 * 8 * 2; // 12,582,912
constexpr size_t SZ_IMG2 = (size_t)128 * 2 * 64 * 64 * 8 * 2; // 16,777,216
constexpr size_t SZ_X1   = (size_t)S_ * B_ * E_ * 2;          // 33,554,432
constexpr size_t SZ_HB   = (size_t)2 * B_ * H_ * 2;           // 262,144
constexpr size_t SZ_ST   = (size_t)4 * B_ * 2 * 4;            // 2,048

constexpr size_t OFF_IMG1 = 0;
constexpr size_t OFF_IMG2 = OFF_IMG1 + SZ_IMG1;
constexpr size_t OFF_X1   = OFF_IMG2 + SZ_IMG2;
constexpr size_t OFF_H1   = OFF_X1 + SZ_X1;
constexpr size_t OFF_H2   = OFF_H1 + SZ_HB;
constexpr size_t OFF_S1   = OFF_H2 + SZ_HB;
constexpr size_t OFF_S2   = OFF_S1 + SZ_ST;
constexpr size_t OFF_GW   = OFF_S2 + SZ_ST;
constexpr size_t OFF_B2E  = OFF_GW + (size_t)Z_ * 4;
constexpr size_t OFF_SYNC = OFF_B2E + (size_t)Z_ * 4;
constexpr size_t OFF_END  = OFF_SYNC + 2048;

// dynamic LDS: [0,131072) weights, [131072, +8448) z tile, then 2*64 floats stats
constexpr int LDS_Z_OFF  = 131072;
constexpr int LDS_SL_OFF = 131072 + 8448;
constexpr int LDS_TOTAL  = LDS_SL_OFF + 512; // 140,032

// ---------------- coherence helpers (hand-rolled, no wbl2 ever) ----------------
// Write-through to the coherence point (MALL); no dirty L2 line left behind.
__device__ __forceinline__ void st_wt_half(_Float16* p, float v) {
    unsigned u = (unsigned)__builtin_bit_cast(unsigned short, (_Float16)v);
    asm volatile("global_store_short %0, %1, off sc0 sc1" :: "v"(p), "v"(u) : "memory");
}
__device__ __forceinline__ void st_wt_f32(float* p, float v) {
    asm volatile("global_store_dword %0, %1, off sc0 sc1" :: "v"(p), "v"(v) : "memory");
}
// Wait for this wave's outstanding vmem (incl. inline-asm stores & atomics).
__device__ __forceinline__ void wait_vm0() {
    asm volatile("s_waitcnt vmcnt(0)" ::: "memory");
}
// Invalidate L1+L2 (tags only; dirty lines like `out` are untouched).
__device__ __forceinline__ void l2_inv() {
    asm volatile("buffer_inv sc1\n\ts_waitcnt vmcnt(0)" ::: "memory");
}

// ---------------- setup kernels ----------------

__global__ void k_zero_ws(float* __restrict__ p, unsigned n) {
    unsigned i = blockIdx.x * 256u + threadIdx.x;
    if (i < n) p[i] = 0.f;
}

// gather emb rows into fp16 x1seq[(t*64+b)][k]
__global__ void k_gather(const int* __restrict__ src, const float* __restrict__ emb,
                         _Float16* __restrict__ x1) {
    int u = blockIdx.x * 256 + threadIdx.x;        // 2,097,152 units of 8 elems
    int k = (u & 63) * 8;
    int rowi = u >> 6;                              // s*64 + b
    int s = rowi >> 6, b = rowi & 63;
    int tok = src[b * S_ + s];
    const float4* ep = (const float4*)(emb + (size_t)tok * E_ + k);
    float4 v0 = ep[0], v1 = ep[1];
    half8 o;
    o[0] = (_Float16)v0.x; o[1] = (_Float16)v0.y; o[2] = (_Float16)v0.z; o[3] = (_Float16)v0.w;
    o[4] = (_Float16)v1.x; o[5] = (_Float16)v1.y; o[6] = (_Float16)v1.z; o[7] = (_Float16)v1.w;
    *(half8*)(x1 + (size_t)rowi * E_ + k) = o;
}

// swizzle weights into MFMA B-fragment order, fp16.
__global__ void k_swz(const float* __restrict__ Wx1, const float* __restrict__ Wh1,
                      const float* __restrict__ Wx2, const float* __restrict__ Wh2,
                      const float* __restrict__ gln1,
                      _Float16* __restrict__ img1, _Float16* __restrict__ img2) {
    int u = blockIdx.x * 256 + threadIdx.x;
    const int U1 = 128 * 2 * 48 * 64;
    if (u < U1) {
        int lane = u & 63; int r = u >> 6;
        int ch = r % 48; r /= 48;
        int nt = r & 1; int bk = r >> 1;
        int n = nt * 16 + (lane & 15);
        int zcol = (n >> 3) * 1024 + bk * 8 + (n & 7);
        int kb = ch * 32 + ((lane >> 4) * 8);
        half8 o;
#pragma unroll
        for (int j = 0; j < 8; ++j) {
            int k = kb + j;
            float v = (k < E_) ? Wx1[(size_t)k * Z_ + zcol] : Wh1[(size_t)(k - E_) * Z_ + zcol];
            o[j] = (_Float16)v;
        }
        *(half8*)(img1 + (size_t)u * 8) = o;
    } else {
        int u2 = u - U1;
        if (u2 >= 128 * 2 * 64 * 64) return;
        int lane = u2 & 63; int r = u2 >> 6;
        int ch = r % 64; r /= 64;
        int nt = r & 1; int bk = r >> 1;
        int n = nt * 16 + (lane & 15);
        int zcol = (n >> 3) * 1024 + bk * 8 + (n & 7);
        int kb = ch * 32 + ((lane >> 4) * 8);
        half8 o;
#pragma unroll
        for (int j = 0; j < 8; ++j) {
            int k = kb + j;
            float v = (k < H_) ? Wx2[(size_t)k * Z_ + zcol] * gln1[k]
                               : Wh2[(size_t)(k - H_) * Z_ + zcol];
            o[j] = (_Float16)v;
        }
        *(half8*)(img2 + (size_t)u2 * 8) = o;
    }
}

// column sums: Gw[c] = sum_k g_ln1[k]*Wx2[k][c]; B2e[c] = b2[c] + sum_k b_ln1[k]*Wx2[k][c]
__global__ void k_colsum(const float* __restrict__ Wx2, const float* __restrict__ gln1,
                         const float* __restrict__ bln1, const float* __restrict__ b2,
                         float* __restrict__ Gw, float* __restrict__ B2e) {
    int c = blockIdx.x * 256 + threadIdx.x;
    if (c >= Z_) return;
    float ag = 0.f, ab = 0.f;
    for (int k = 0; k < H_; ++k) {
        float w = Wx2[(size_t)k * Z_ + c];
        ag += gln1[k] * w;
        ab += bln1[k] * w;
    }
    Gw[c] = ag;
    B2e[c] = b2[c] + ab;
}

// ---------------- persistent recurrent kernel ----------------

__device__ __forceinline__ float sigm_(float x) { return 1.f / (1.f + __expf(-x)); }
__device__ __forceinline__ float tanh_(float x) { return 1.f - 2.f / (__expf(2.f * x) + 1.f); }

__global__ void __launch_bounds__(256, 1)
k_rnn(const float* __restrict__ b1,
      const float* __restrict__ gln2, const float* __restrict__ bln2,
      const _Float16* __restrict__ img1, const _Float16* __restrict__ img2,
      const _Float16* __restrict__ x1seq,
      _Float16* __restrict__ h1buf, _Float16* __restrict__ h2buf,
      float* __restrict__ s1, float* __restrict__ s2,
      const float* __restrict__ Gw, const float* __restrict__ B2e,
      unsigned int* __restrict__ gsync,
      float* __restrict__ out) {
    extern __shared__ char smem[];
    float* zl = (float*)(smem + LDS_Z_OFF);          // [64][33] padded
    float* sl_mean = (float*)(smem + LDS_SL_OFF);    // [64]
    float* sl_inv = sl_mean + 64;                    // [64]

    const int tid = threadIdx.x;
    const int bid = blockIdx.x;
    const bool is2 = bid >= 128;
    const int bk = is2 ? bid - 128 : bid;
    const int wv = tid >> 6, lane = tid & 63;
    const int quad = lane >> 4, m15 = lane & 15;
    const int hc = tid & 7;
    const int b0 = tid >> 3;          // 0..31
    const int col = bk * 8 + hc;
    const int row = wv * 16 + m15;    // A-operand batch row

    // stage pre-swizzled weights into LDS
    {
        const uint4* s = (const uint4*)(is2 ? (img2 + (size_t)bk * (2 * 64 * 64 * 8))
                                            : (img1 + (size_t)bk * (2 * 48 * 64 * 8)));
        uint4* d = (uint4*)smem;
        int n16 = is2 ? (131072 / 16) : (98304 / 16);
        for (int i = tid; i < n16; i += 256) d[i] = s[i];
    }

    float bias[4], gl2v = 0.f, bl2v = 0.f, gw0 = 0.f, gw1 = 0.f;
    if (!is2) {
#pragma unroll
        for (int g = 0; g < 4; ++g) bias[g] = b1[g * 1024 + col];
    } else {
#pragma unroll
        for (int g = 0; g < 4; ++g) bias[g] = B2e[g * 1024 + col];
        gl2v = gln2[col]; bl2v = bln2[col];
        int na = m15, nb = 16 + m15;
        gw0 = Gw[(na >> 3) * 1024 + bk * 8 + (na & 7)];
        gw1 = Gw[(nb >> 3) * 1024 + bk * 8 + (nb & 7)];
    }
    float c_own[2] = {0.f, 0.f}, h_own[2] = {0.f, 0.f};

    __syncthreads();
    const half8* wb = (const half8*)smem;

    // x-part prefetch accumulators (layer-1 only): x@Wx contribution for step t,
    // computed during phase t-1 (depends only on read-only x1seq + LDS weights).
    f32x4 xa0 = {0.f, 0.f, 0.f, 0.f}, xa1 = {0.f, 0.f, 0.f, 0.f};
    if (!is2) {
        const half8* xp = (const half8*)(x1seq + (size_t)row * E_ + quad * 8);
#pragma unroll 4
        for (int ch = 0; ch < 16; ++ch) {
            half8 a = xp[ch * 4];
            xa0 = __builtin_amdgcn_mfma_f32_16x16x32_f16(a, wb[(0 * 48 + ch) * 64 + lane], xa0, 0, 0, 0);
            xa1 = __builtin_amdgcn_mfma_f32_16x16x32_f16(a, wb[(1 * 48 + ch) * 64 + lane], xa1, 0, 0, 0);
        }
    }

    for (int t = 0; t <= S_ + 1; ++t) {
        if (!is2) {
            // ---------------- layer-1 cell, step t ----------------
            if (t < S_) {
                f32x4 a0 = xa0, a1 = xa1;   // x-part (prefetched)
                const half8* hp = (const half8*)(h1buf + (size_t)((t + 1) & 1) * (B_ * H_) + (size_t)row * H_ + quad * 8);
#pragma unroll 4
                for (int ch = 0; ch < 32; ++ch) {
                    half8 a = hp[ch * 4];
                    a0 = __builtin_amdgcn_mfma_f32_16x16x32_f16(a, wb[(0 * 48 + 16 + ch) * 64 + lane], a0, 0, 0, 0);
                    a1 = __builtin_amdgcn_mfma_f32_16x16x32_f16(a, wb[(1 * 48 + 16 + ch) * 64 + lane], a1, 0, 0, 0);
                }
#pragma unroll
                for (int r = 0; r < 4; ++r) {
                    int orow = wv * 16 + quad * 4 + r;
                    zl[orow * 33 + m15] = a0[r];
                    zl[orow * 33 + 16 + m15] = a1[r];
                }
                __syncthreads();
#pragma unroll
                for (int p = 0; p < 2; ++p) {
                    int b = b0 + 32 * p;
                    float iv = zl[b * 33 + hc] + bias[0];
                    float fv = zl[b * 33 + 8 + hc] + bias[1];
                    float ov = zl[b * 33 + 16 + hc] + bias[2];
                    float gv = zl[b * 33 + 24 + hc] + bias[3];
                    float c = sigm_(fv) * c_own[p] + sigm_(iv) * tanh_(gv);
                    float h = sigm_(ov) * tanh_(c);
                    c_own[p] = c; h_own[p] = h;
                    st_wt_half(h1buf + (size_t)(t & 1) * (B_ * H_) + (size_t)b * H_ + col, h);
                    float sm = h, sq = h * h;
                    sm += __shfl_xor(sm, 1); sm += __shfl_xor(sm, 2); sm += __shfl_xor(sm, 4);
                    sq += __shfl_xor(sq, 1); sq += __shfl_xor(sq, 2); sq += __shfl_xor(sq, 4);
                    if (hc == 0) {
                        atomicAdd(&s1[(size_t)(t & 3) * 128 + b * 2 + 0], sm);
                        atomicAdd(&s1[(size_t)(t & 3) * 128 + b * 2 + 1], sq);
                    }
                }
                // prefetch x-part for step t+1 while the h-stores drain
                if (t + 1 < S_) {
                    xa0 = (f32x4){0.f, 0.f, 0.f, 0.f};
                    xa1 = (f32x4){0.f, 0.f, 0.f, 0.f};
                    const half8* xp = (const half8*)(x1seq + (size_t)((t + 1) * 64 + row) * E_ + quad * 8);
#pragma unroll 4
                    for (int ch = 0; ch < 16; ++ch) {
                        half8 a = xp[ch * 4];
                        xa0 = __builtin_amdgcn_mfma_f32_16x16x32_f16(a, wb[(0 * 48 + ch) * 64 + lane], xa0, 0, 0, 0);
                        xa1 = __builtin_amdgcn_mfma_f32_16x16x32_f16(a, wb[(1 * 48 + ch) * 64 + lane], xa1, 0, 0, 0);
                    }
                }
            }
            if (tid == 0 && bk < 64) { // zero stats slot to be written next phase
                st_wt_f32(&s1[(size_t)((t + 1) & 3) * 128 + bk * 2 + 0], 0.f);
                st_wt_f32(&s1[(size_t)((t + 1) & 3) * 128 + bk * 2 + 1], 0.f);
            }
        } else {
            // ---------------- layer-2 cell, step t-1 (+ output LN of step t-2) ----------------
            if (t >= 2) {
                int to = t - 2;
#pragma unroll
                for (int p = 0; p < 2; ++p) {
                    int b = b0 + 32 * p;
                    float sm = s2[(size_t)(to & 3) * 128 + b * 2 + 0];
                    float sq = s2[(size_t)(to & 3) * 128 + b * 2 + 1];
                    float mean = sm * (1.f / 1024.f);
                    float inv = rsqrtf(sq * (1.f / 1024.f) - mean * mean + 1e-5f);
                    out[(size_t)b * (S_ * H_) + (size_t)to * H_ + col] =
                        (h_own[p] - mean) * inv * gl2v + bl2v;
                }
            }
            if (t >= 1 && t <= S_) {
                int tt = t - 1;
                if (tid < 64) {
                    float sm = s1[(size_t)(tt & 3) * 128 + tid * 2 + 0];
                    float sq = s1[(size_t)(tt & 3) * 128 + tid * 2 + 1];
                    float mean = sm * (1.f / 1024.f);
                    sl_mean[tid] = mean;
                    sl_inv[tid] = rsqrtf(sq * (1.f / 1024.f) - mean * mean + 1e-5f);
                }
                f32x4 ax0 = {0.f, 0.f, 0.f, 0.f}, ax1 = {0.f, 0.f, 0.f, 0.f};
                f32x4 ah0 = {0.f, 0.f, 0.f, 0.f}, ah1 = {0.f, 0.f, 0.f, 0.f};
                const half8* hp1 = (const half8*)(h1buf + (size_t)(tt & 1) * (B_ * H_) + (size_t)row * H_ + quad * 8);
#pragma unroll 4
                for (int ch = 0; ch < 32; ++ch) {
                    half8 a = hp1[ch * 4];
                    ax0 = __builtin_amdgcn_mfma_f32_16x16x32_f16(a, wb[(0 * 64 + ch) * 64 + lane], ax0, 0, 0, 0);
                    ax1 = __builtin_amdgcn_mfma_f32_16x16x32_f16(a, wb[(1 * 64 + ch) * 64 + lane], ax1, 0, 0, 0);
                }
                const half8* hp2 = (const half8*)(h2buf + (size_t)(t & 1) * (B_ * H_) + (size_t)row * H_ + quad * 8);
#pragma unroll 4
                for (int ch = 0; ch < 32; ++ch) {
                    half8 a = hp2[ch * 4];
                    ah0 = __builtin_amdgcn_mfma_f32_16x16x32_f16(a, wb[(0 * 64 + 32 + ch) * 64 + lane], ah0, 0, 0, 0);
                    ah1 = __builtin_amdgcn_mfma_f32_16x16x32_f16(a, wb[(1 * 64 + 32 + ch) * 64 + lane], ah1, 0, 0, 0);
                }
                __syncthreads(); // sl ready; zl free
#pragma unroll
                for (int r = 0; r < 4; ++r) {
                    int orow = wv * 16 + quad * 4 + r;
                    float m = sl_mean[orow], iv = sl_inv[orow];
                    zl[orow * 33 + m15] = (ax0[r] - m * gw0) * iv + ah0[r];
                    zl[orow * 33 + 16 + m15] = (ax1[r] - m * gw1) * iv + ah1[r];
                }
                __syncthreads();
#pragma unroll
                for (int p = 0; p < 2; ++p) {
                    int b = b0 + 32 * p;
                    float iv = zl[b * 33 + hc] + bias[0];
                    float fv = zl[b * 33 + 8 + hc] + bias[1];
                    float ov = zl[b * 33 + 16 + hc] + bias[2];
                    float gv = zl[b * 33 + 24 + hc] + bias[3];
                    float c = sigm_(fv) * c_own[p] + sigm_(iv) * tanh_(gv);
                    float h = sigm_(ov) * tanh_(c);
                    c_own[p] = c; h_own[p] = h;
                    st_wt_half(h2buf + (size_t)(tt & 1) * (B_ * H_) + (size_t)b * H_ + col, h);
                    float sm = h, sq = h * h;
                    sm += __shfl_xor(sm, 1); sm += __shfl_xor(sm, 2); sm += __shfl_xor(sm, 4);
                    sq += __shfl_xor(sq, 1); sq += __shfl_xor(sq, 2); sq += __shfl_xor(sq, 4);
                    if (hc == 0) {
                        atomicAdd(&s2[(size_t)(tt & 3) * 128 + b * 2 + 0], sm);
                        atomicAdd(&s2[(size_t)(tt & 3) * 128 + b * 2 + 1], sq);
                    }
                }
            }
            if (tid == 0 && bk < 64) {
                st_wt_f32(&s2[(size_t)(t & 3) * 128 + bk * 2 + 0], 0.f);
                st_wt_f32(&s2[(size_t)(t & 3) * 128 + bk * 2 + 1], 0.f);
            }
        }

        // ---------------- grid barrier (two-level, fully relaxed) ----------------
        if (t <= S_) {
            wait_vm0();          // drain this wave's write-through stores/atomics to MALL
            __syncthreads();
            if (tid == 0) {
                int grp = bid & 7;
                unsigned old = __hip_atomic_fetch_add(&gsync[32 * (grp + 1)], 1u,
                                                      __ATOMIC_RELAXED, __HIP_MEMORY_SCOPE_AGENT);
                if (old == 32u * (unsigned)(t + 1) - 1u) {
                    __hip_atomic_fetch_add(&gsync[0], 1u, __ATOMIC_RELAXED, __HIP_MEMORY_SCOPE_AGENT);
                }
                unsigned tgt = 8u * (unsigned)(t + 1);
                while (__hip_atomic_load(&gsync[0], __ATOMIC_RELAXED, __HIP_MEMORY_SCOPE_AGENT) < tgt) {
                    __builtin_amdgcn_s_sleep(2);
                }
            }
            __syncthreads();
            l2_inv();            // one tag-invalidate per wave per step; next loads hit MALL-fresh data
        }
    }

    // ---------------- finals ----------------
    const size_t BASE_H = (size_t)B_ * S_ * H_;
    const size_t BASE_C = BASE_H + (size_t)B_ * 2 * H_;
    int cc = is2 ? (1024 + col) : col;
#pragma unroll
    for (int p = 0; p < 2; ++p) {
        int b = b0 + 32 * p;
        out[BASE_H + (size_t)b * 2048 + cc] = h_own[p];
        out[BASE_C + (size_t)b * 2048 + cc] = c_own[p];
    }
}

// ---------------- host ----------------

extern "C" void kernel_launch(void* const* d_in, const int* in_sizes, int n_in,
                              void* d_out, int out_size, void* d_ws, size_t ws_size,
                              hipStream_t stream) {
    const int* src = (const int*)d_in[0];
    const float* emb = (const float*)d_in[1];
    const float* Wx1 = (const float*)d_in[2];
    const float* Wh1 = (const float*)d_in[3];
    const float* b1 = (const float*)d_in[4];
    const float* Wx2 = (const float*)d_in[5];
    const float* Wh2 = (const float*)d_in[6];
    const float* b2 = (const float*)d_in[7];
    const float* gl1 = (const float*)d_in[8];
    const float* bl1 = (const float*)d_in[9];
    const float* gl2 = (const float*)d_in[10];
    const float* bl2 = (const float*)d_in[11];
    float* out = (float*)d_out;
    char* ws = (char*)d_ws;
    if (ws_size < OFF_END) return;

    _Float16* img1 = (_Float16*)(ws + OFF_IMG1);
    _Float16* img2 = (_Float16*)(ws + OFF_IMG2);
    _Float16* x1seq = (_Float16*)(ws + OFF_X1);
    _Float16* h1buf = (_Float16*)(ws + OFF_H1);
    _Float16* h2buf = (_Float16*)(ws + OFF_H2);
    float* s1 = (float*)(ws + OFF_S1);
    float* s2 = (float*)(ws + OFF_S2);
    float* Gw = (float*)(ws + OFF_GW);
    float* B2e = (float*)(ws + OFF_B2E);
    unsigned int* gsync = (unsigned int*)(ws + OFF_SYNC);

    (void)hipFuncSetAttribute((const void*)k_rnn,
                              hipFuncAttributeMaxDynamicSharedMemorySize, LDS_TOTAL);

    unsigned zero_n = (unsigned)((OFF_END - OFF_H1) / 4);
    k_zero_ws<<<(zero_n + 255) / 256, 256, 0, stream>>>((float*)(ws + OFF_H1), zero_n);
    k_gather<<<8192, 256, 0, stream>>>(src, emb, x1seq);
    k_swz<<<7168, 256, 0, stream>>>(Wx1, Wh1, Wx2, Wh2, gl1, img1, img2);
    k_colsum<<<16, 256, 0, stream>>>(Wx2, gl1, bl1, b2, Gw, B2e);
    k_rnn<<<256, 256, LDS_TOTAL, stream>>>(b1, gl2, bl2, img1, img2, x1seq,
                                           h1buf, h2buf, s1, s2, Gw, B2e, gsync, out);
}

// Round 5
// 8167.776 us; speedup vs baseline: 2.4185x; 1.7540x over previous
//
#include <hip/hip_runtime.h>
#include <math.h>

// Problem constants
#define S_ 512
#define B_ 64
#define E_ 512
#define H_ 1024
#define Z_ 4096

typedef _Float16 half8 __attribute__((ext_vector_type(8)));
typedef float f32x4 __attribute__((ext_vector_type(4)));

// ---------------- workspace layout (bytes) ----------------
constexpr size_t SZ_IMG1 = (size_t)128 * 2 * 48 * 64 * 8 * 2; // 12,582,912
constexpr size_t SZ_IMG2 = (size_t)128 * 2 * 64 * 64 * 8 * 2; // 16,777,216
constexpr size_t SZ_X1   = (size_t)S_ * B_ * E_ * 2;          // 33,554,432
constexpr size_t SZ_HB   = (size_t)2 * B_ * H_ * 2;           // 262,144 (two slots)
constexpr size_t SZ_ST   = (size_t)4 * B_ * 2 * 4;            // 2,048

constexpr size_t OFF_IMG1 = 0;
constexpr size_t OFF_IMG2 = OFF_IMG1 + SZ_IMG1;
constexpr size_t OFF_X1   = OFF_IMG2 + SZ_IMG2;
constexpr size_t OFF_H1   = OFF_X1 + SZ_X1;
constexpr size_t OFF_H2   = OFF_H1 + SZ_HB;
constexpr size_t OFF_S1   = OFF_H2 + SZ_HB;
constexpr size_t OFF_S2   = OFF_S1 + SZ_ST;
constexpr size_t OFF_GW   = OFF_S2 + SZ_ST;
constexpr size_t OFF_B2E  = OFF_GW + (size_t)Z_ * 4;
constexpr size_t OFF_SYNC = OFF_B2E + (size_t)Z_ * 4;
constexpr size_t OFF_END  = OFF_SYNC + 2048;

// dynamic LDS: [0,131072) weights, [131072, +8448) z tile, then 2*64 floats stats
constexpr int LDS_Z_OFF  = 131072;
constexpr int LDS_SL_OFF = 131072 + 8448;
constexpr int LDS_TOTAL  = LDS_SL_OFF + 512; // 140,032

// ---------------- coherence helpers ----------------
// Cross-block traffic: write-through (sc0 sc1) stores + bypass (sc0 sc1) loads.
// No cache maintenance ops anywhere. ALL register ties use vmcnt(0) ONLY —
// a full drain is correct regardless of compiler-inserted vmem (spills etc.);
// non-zero vmcnt arithmetic proved un-robust (r3: NaN, r4: abort).
__device__ __forceinline__ void st_wt_half(_Float16* p, float v) {
    unsigned u = (unsigned)__builtin_bit_cast(unsigned short, (_Float16)v);
    asm volatile("global_store_short %0, %1, off sc0 sc1" :: "v"(p), "v"(u) : "memory");
}
__device__ __forceinline__ void st_wt_f32(float* p, float v) {
    asm volatile("global_store_dword %0, %1, off sc0 sc1" :: "v"(p), "v"(v) : "memory");
}
__device__ __forceinline__ void wait_vm0() {
    asm volatile("s_waitcnt vmcnt(0)" ::: "memory");
}
__device__ __forceinline__ void ld_h8_sys(half8* d, const _Float16* p) {
    asm volatile("global_load_dwordx4 %0, %1, off sc0 sc1" : "=v"(*d) : "v"(p) : "memory");
}
__device__ __forceinline__ void ld_f32_sys(float* d, const float* p) {
    asm volatile("global_load_dword %0, %1, off sc0 sc1" : "=v"(*d) : "v"(p) : "memory");
}
// full-drain register ties (always vmcnt(0))
#define TIE16Z(r) asm volatile("s_waitcnt vmcnt(0)" : \
    "+v"(r[0]),"+v"(r[1]),"+v"(r[2]),"+v"(r[3]),"+v"(r[4]),"+v"(r[5]),"+v"(r[6]),"+v"(r[7]), \
    "+v"(r[8]),"+v"(r[9]),"+v"(r[10]),"+v"(r[11]),"+v"(r[12]),"+v"(r[13]),"+v"(r[14]),"+v"(r[15]) \
    :: "memory")
#define TIE6FZ(f0,f1,f2,f3,f4,f5) asm volatile("s_waitcnt vmcnt(0)" : \
    "+v"(f0),"+v"(f1),"+v"(f2),"+v"(f3),"+v"(f4),"+v"(f5) :: "memory")
#define TIE4FZ(f0,f1,f2,f3) asm volatile("s_waitcnt vmcnt(0)" : \
    "+v"(f0),"+v"(f1),"+v"(f2),"+v"(f3) :: "memory")

// ---------------- setup kernels ----------------

__global__ void k_zero_ws(float* __restrict__ p, unsigned n) {
    unsigned i = blockIdx.x * 256u + threadIdx.x;
    if (i < n) p[i] = 0.f;
}

// gather emb rows into fp16 x1seq[(t*64+b)][k]
__global__ void k_gather(const int* __restrict__ src, const float* __restrict__ emb,
                         _Float16* __restrict__ x1) {
    int u = blockIdx.x * 256 + threadIdx.x;        // 2,097,152 units of 8 elems
    int k = (u & 63) * 8;
    int rowi = u >> 6;                              // s*64 + b
    int s = rowi >> 6, b = rowi & 63;
    int tok = src[b * S_ + s];
    const float4* ep = (const float4*)(emb + (size_t)tok * E_ + k);
    float4 v0 = ep[0], v1 = ep[1];
    half8 o;
    o[0] = (_Float16)v0.x; o[1] = (_Float16)v0.y; o[2] = (_Float16)v0.z; o[3] = (_Float16)v0.w;
    o[4] = (_Float16)v1.x; o[5] = (_Float16)v1.y; o[6] = (_Float16)v1.z; o[7] = (_Float16)v1.w;
    *(half8*)(x1 + (size_t)rowi * E_ + k) = o;
}

// swizzle weights into MFMA B-fragment order, fp16.
__global__ void k_swz(const float* __restrict__ Wx1, const float* __restrict__ Wh1,
                      const float* __restrict__ Wx2, const float* __restrict__ Wh2,
                      const float* __restrict__ gln1,
                      _Float16* __restrict__ img1, _Float16* __restrict__ img2) {
    int u = blockIdx.x * 256 + threadIdx.x;
    const int U1 = 128 * 2 * 48 * 64;
    if (u < U1) {
        int lane = u & 63; int r = u >> 6;
        int ch = r % 48; r /= 48;
        int nt = r & 1; int bk = r >> 1;
        int n = nt * 16 + (lane & 15);
        int zcol = (n >> 3) * 1024 + bk * 8 + (n & 7);
        int kb = ch * 32 + ((lane >> 4) * 8);
        half8 o;
#pragma unroll
        for (int j = 0; j < 8; ++j) {
            int k = kb + j;
            float v = (k < E_) ? Wx1[(size_t)k * Z_ + zcol] : Wh1[(size_t)(k - E_) * Z_ + zcol];
            o[j] = (_Float16)v;
        }
        *(half8*)(img1 + (size_t)u * 8) = o;
    } else {
        int u2 = u - U1;
        if (u2 >= 128 * 2 * 64 * 64) return;
        int lane = u2 & 63; int r = u2 >> 6;
        int ch = r % 64; r /= 64;
        int nt = r & 1; int bk = r >> 1;
        int n = nt * 16 + (lane & 15);
        int zcol = (n >> 3) * 1024 + bk * 8 + (n & 7);
        int kb = ch * 32 + ((lane >> 4) * 8);
        half8 o;
#pragma unroll
        for (int j = 0; j < 8; ++j) {
            int k = kb + j;
            float v = (k < H_) ? Wx2[(size_t)k * Z_ + zcol] * gln1[k]
                               : Wh2[(size_t)(k - H_) * Z_ + zcol];
            o[j] = (_Float16)v;
        }
        *(half8*)(img2 + (size_t)u2 * 8) = o;
    }
}

// column sums: Gw[c] = sum_k g_ln1[k]*Wx2[k][c]; B2e[c] = b2[c] + sum_k b_ln1[k]*Wx2[k][c]
__global__ void k_colsum(const float* __restrict__ Wx2, const float* __restrict__ gln1,
                         const float* __restrict__ bln1, const float* __restrict__ b2,
                         float* __restrict__ Gw, float* __restrict__ B2e) {
    int c = blockIdx.x * 256 + threadIdx.x;
    if (c >= Z_) return;
    float ag = 0.f, ab = 0.f;
    for (int k = 0; k < H_; ++k) {
        float w = Wx2[(size_t)k * Z_ + c];
        ag += gln1[k] * w;
        ab += bln1[k] * w;
    }
    Gw[c] = ag;
    B2e[c] = b2[c] + ab;
}

// ---------------- persistent recurrent kernel ----------------

__device__ __forceinline__ float sigm_(float x) { return 1.f / (1.f + __expf(-x)); }
__device__ __forceinline__ float tanh_(float x) { return 1.f - 2.f / (__expf(2.f * x) + 1.f); }

__device__ __forceinline__ f32x4 mfma16(half8 a, half8 b, f32x4 c) {
    return __builtin_amdgcn_mfma_f32_16x16x32_f16(a, b, c, 0, 0, 0);
}

// h buffers layout: [slot][kblk(128)][b(64)][8]  (elem offset = kblk*512 + b*8 + j)
// writer (block kblk): block stores 512 B contiguous per p; reader A-frag chunk ch:
// half8 index (ch*4+quad)*64 + row  (256 B contiguous per quad)

__global__ void __launch_bounds__(256, 1)
k_rnn(const float* __restrict__ b1,
      const float* __restrict__ gln2, const float* __restrict__ bln2,
      const _Float16* __restrict__ img1, const _Float16* __restrict__ img2,
      const _Float16* __restrict__ x1seq,
      _Float16* __restrict__ h1buf, _Float16* __restrict__ h2buf,
      float* __restrict__ s1, float* __restrict__ s2,
      const float* __restrict__ Gw, const float* __restrict__ B2e,
      unsigned int* __restrict__ gsync,
      float* __restrict__ out) {
    extern __shared__ char smem[];
    float* zl = (float*)(smem + LDS_Z_OFF);          // [64][33] padded
    float* sl_mean = (float*)(smem + LDS_SL_OFF);    // [64]
    float* sl_inv = sl_mean + 64;                    // [64]

    const int tid = threadIdx.x;
    const int bid = blockIdx.x;
    const bool is2 = bid >= 128;
    const int bk = is2 ? bid - 128 : bid;
    const int wv = tid >> 6, lane = tid & 63;
    const int quad = lane >> 4, m15 = lane & 15;
    const int hc = tid & 7;
    const int b0 = tid >> 3;          // 0..31
    const int col = bk * 8 + hc;
    const int row = wv * 16 + m15;    // A-operand batch row

    // stage pre-swizzled weights into LDS
    {
        const uint4* s = (const uint4*)(is2 ? (img2 + (size_t)bk * (2 * 64 * 64 * 8))
                                            : (img1 + (size_t)bk * (2 * 48 * 64 * 8)));
        uint4* d = (uint4*)smem;
        int n16 = is2 ? (131072 / 16) : (98304 / 16);
        for (int i = tid; i < n16; i += 256) d[i] = s[i];
    }

    float bias[4], gl2v = 0.f, bl2v = 0.f, gw0 = 0.f, gw1 = 0.f;
    if (!is2) {
#pragma unroll
        for (int g = 0; g < 4; ++g) bias[g] = b1[g * 1024 + col];
    } else {
#pragma unroll
        for (int g = 0; g < 4; ++g) bias[g] = B2e[g * 1024 + col];
        gl2v = gln2[col]; bl2v = bln2[col];
        int na = m15, nb = 16 + m15;
        gw0 = Gw[(na >> 3) * 1024 + bk * 8 + (na & 7)];
        gw1 = Gw[(nb >> 3) * 1024 + bk * 8 + (nb & 7)];
    }
    float c_own[2] = {0.f, 0.f}, h_own[2] = {0.f, 0.f};

    __syncthreads();
    const half8* wb = (const half8*)smem;

    // x-part prefetch accumulators (layer-1 only)
    f32x4 xa0 = {0.f, 0.f, 0.f, 0.f}, xa1 = {0.f, 0.f, 0.f, 0.f};
    if (!is2) {
        const half8* xp = (const half8*)(x1seq + (size_t)row * E_ + quad * 8);
#pragma unroll 4
        for (int ch = 0; ch < 16; ++ch) {
            half8 a = xp[ch * 4];
            xa0 = mfma16(a, wb[(0 * 48 + ch) * 64 + lane], xa0);
            xa1 = mfma16(a, wb[(1 * 48 + ch) * 64 + lane], xa1);
        }
    }

    for (int t = 0; t <= S_ + 1; ++t) {
        if (!is2) {
            // ---------------- layer-1 cell, step t ----------------
            if (t < S_) {
                half8 hA[16], hB[16];
                const _Float16* hb = h1buf + (size_t)((t + 1) & 1) * 65536;
#pragma unroll
                for (int i = 0; i < 16; ++i)
                    ld_h8_sys(&hA[i], hb + (((i * 4 + quad) * 64 + row) << 3));
#pragma unroll
                for (int i = 0; i < 16; ++i)
                    ld_h8_sys(&hB[i], hb + ((((16 + i) * 4 + quad) * 64 + row) << 3));
                TIE16Z(hA);
                TIE16Z(hB);
                f32x4 a0 = xa0, a1 = xa1;
#pragma unroll
                for (int ch = 0; ch < 16; ++ch) {
                    a0 = mfma16(hA[ch], wb[(0 * 48 + 16 + ch) * 64 + lane], a0);
                    a1 = mfma16(hA[ch], wb[(1 * 48 + 16 + ch) * 64 + lane], a1);
                }
#pragma unroll
                for (int ch = 0; ch < 16; ++ch) {
                    a0 = mfma16(hB[ch], wb[(0 * 48 + 32 + ch) * 64 + lane], a0);
                    a1 = mfma16(hB[ch], wb[(1 * 48 + 32 + ch) * 64 + lane], a1);
                }
#pragma unroll
                for (int r = 0; r < 4; ++r) {
                    int orow = wv * 16 + quad * 4 + r;
                    zl[orow * 33 + m15] = a0[r];
                    zl[orow * 33 + 16 + m15] = a1[r];
                }
                __syncthreads();
#pragma unroll
                for (int p = 0; p < 2; ++p) {
                    int b = b0 + 32 * p;
                    float iv = zl[b * 33 + hc] + bias[0];
                    float fv = zl[b * 33 + 8 + hc] + bias[1];
                    float ov = zl[b * 33 + 16 + hc] + bias[2];
                    float gv = zl[b * 33 + 24 + hc] + bias[3];
                    float c = sigm_(fv) * c_own[p] + sigm_(iv) * tanh_(gv);
                    float h = sigm_(ov) * tanh_(c);
                    c_own[p] = c; h_own[p] = h;
                    st_wt_half(h1buf + (size_t)(t & 1) * 65536 + (size_t)bk * 512 + b * 8 + hc, h);
                    float sm = h, sq = h * h;
                    sm += __shfl_xor(sm, 1); sm += __shfl_xor(sm, 2); sm += __shfl_xor(sm, 4);
                    sq += __shfl_xor(sq, 1); sq += __shfl_xor(sq, 2); sq += __shfl_xor(sq, 4);
                    if (hc == 0) {
                        atomicAdd(&s1[(size_t)(t & 3) * 128 + b * 2 + 0], sm);
                        atomicAdd(&s1[(size_t)(t & 3) * 128 + b * 2 + 1], sq);
                    }
                }
                // prefetch x-part for step t+1 while the h-stores drain
                if (t + 1 < S_) {
                    xa0 = (f32x4){0.f, 0.f, 0.f, 0.f};
                    xa1 = (f32x4){0.f, 0.f, 0.f, 0.f};
                    const half8* xp = (const half8*)(x1seq + (size_t)((t + 1) * 64 + row) * E_ + quad * 8);
#pragma unroll 4
                    for (int ch = 0; ch < 16; ++ch) {
                        half8 a = xp[ch * 4];
                        xa0 = mfma16(a, wb[(0 * 48 + ch) * 64 + lane], xa0);
                        xa1 = mfma16(a, wb[(1 * 48 + ch) * 64 + lane], xa1);
                    }
                }
            }
            if (tid == 0 && bk < 64) { // zero stats slot to be written next phase
                st_wt_f32(&s1[(size_t)((t + 1) & 3) * 128 + bk * 2 + 0], 0.f);
                st_wt_f32(&s1[(size_t)((t + 1) & 3) * 128 + bk * 2 + 1], 0.f);
            }
        } else {
            // ---------------- layer-2 cell, step t-1 (+ output LN of step t-2) ----------------
            float o_sm0 = 0.f, o_sq0 = 0.f, o_sm1 = 0.f, o_sq1 = 0.f;
            float st_sm = 0.f, st_sq = 0.f;
            const bool do_out = (t >= 2);
            const bool do_cell = (t >= 1 && t <= S_);
            if (do_cell) {
                int tt = t - 1;
                // issue stats + h1 (A,B); drain; issue h2 (C,D); h1 MFMAs; drain; h2 MFMAs
                if (do_out) {
                    const float* sp = s2 + (size_t)((t - 2) & 3) * 128;
                    ld_f32_sys(&o_sm0, sp + b0 * 2 + 0);
                    ld_f32_sys(&o_sq0, sp + b0 * 2 + 1);
                    ld_f32_sys(&o_sm1, sp + (b0 + 32) * 2 + 0);
                    ld_f32_sys(&o_sq1, sp + (b0 + 32) * 2 + 1);
                }
                if (tid < 64) {   // wave 0 only (wave-uniform divergence)
                    const float* sp1 = s1 + (size_t)(tt & 3) * 128;
                    ld_f32_sys(&st_sm, sp1 + tid * 2 + 0);
                    ld_f32_sys(&st_sq, sp1 + tid * 2 + 1);
                }
                half8 A[16], B[16], C[16], D[16];
                const _Float16* p1 = h1buf + (size_t)((t + 1) & 1) * 65536;
                const _Float16* p2 = h2buf + (size_t)(t & 1) * 65536;
#pragma unroll
                for (int i = 0; i < 16; ++i)
                    ld_h8_sys(&A[i], p1 + (((i * 4 + quad) * 64 + row) << 3));
#pragma unroll
                for (int i = 0; i < 16; ++i)
                    ld_h8_sys(&B[i], p1 + ((((16 + i) * 4 + quad) * 64 + row) << 3));
                TIE16Z(A);
                TIE16Z(B);
                TIE6FZ(o_sm0, o_sq0, o_sm1, o_sq1, st_sm, st_sq);
                // h2 loads fly while h1 MFMAs run
#pragma unroll
                for (int i = 0; i < 16; ++i)
                    ld_h8_sys(&C[i], p2 + (((i * 4 + quad) * 64 + row) << 3));
#pragma unroll
                for (int i = 0; i < 16; ++i)
                    ld_h8_sys(&D[i], p2 + ((((16 + i) * 4 + quad) * 64 + row) << 3));
                f32x4 ax0 = {0.f, 0.f, 0.f, 0.f}, ax1 = {0.f, 0.f, 0.f, 0.f};
                f32x4 ah0 = {0.f, 0.f, 0.f, 0.f}, ah1 = {0.f, 0.f, 0.f, 0.f};
#pragma unroll
                for (int ch = 0; ch < 16; ++ch) {
                    ax0 = mfma16(A[ch], wb[(0 * 64 + ch) * 64 + lane], ax0);
                    ax1 = mfma16(A[ch], wb[(1 * 64 + ch) * 64 + lane], ax1);
                }
#pragma unroll
                for (int ch = 0; ch < 16; ++ch) {
                    ax0 = mfma16(B[ch], wb[(0 * 64 + 16 + ch) * 64 + lane], ax0);
                    ax1 = mfma16(B[ch], wb[(1 * 64 + 16 + ch) * 64 + lane], ax1);
                }
                TIE16Z(C);
                TIE16Z(D);
#pragma unroll
                for (int ch = 0; ch < 16; ++ch) {
                    ah0 = mfma16(C[ch], wb[(0 * 64 + 32 + ch) * 64 + lane], ah0);
                    ah1 = mfma16(C[ch], wb[(1 * 64 + 32 + ch) * 64 + lane], ah1);
                }
#pragma unroll
                for (int ch = 0; ch < 16; ++ch) {
                    ah0 = mfma16(D[ch], wb[(0 * 64 + 48 + ch) * 64 + lane], ah0);
                    ah1 = mfma16(D[ch], wb[(1 * 64 + 48 + ch) * 64 + lane], ah1);
                }
                // output LN of step t-2 (h_own not yet updated)
                if (do_out) {
                    int to = t - 2;
                    float mean = o_sm0 * (1.f / 1024.f);
                    float inv = rsqrtf(o_sq0 * (1.f / 1024.f) - mean * mean + 1e-5f);
                    out[(size_t)b0 * (S_ * H_) + (size_t)to * H_ + col] =
                        (h_own[0] - mean) * inv * gl2v + bl2v;
                    mean = o_sm1 * (1.f / 1024.f);
                    inv = rsqrtf(o_sq1 * (1.f / 1024.f) - mean * mean + 1e-5f);
                    out[(size_t)(b0 + 32) * (S_ * H_) + (size_t)to * H_ + col] =
                        (h_own[1] - mean) * inv * gl2v + bl2v;
                }
                if (tid < 64) {
                    float mean = st_sm * (1.f / 1024.f);
                    sl_mean[tid] = mean;
                    sl_inv[tid] = rsqrtf(st_sq * (1.f / 1024.f) - mean * mean + 1e-5f);
                }
                __syncthreads(); // sl ready; zl free
#pragma unroll
                for (int r = 0; r < 4; ++r) {
                    int orow = wv * 16 + quad * 4 + r;
                    float m = sl_mean[orow], iv = sl_inv[orow];
                    zl[orow * 33 + m15] = (ax0[r] - m * gw0) * iv + ah0[r];
                    zl[orow * 33 + 16 + m15] = (ax1[r] - m * gw1) * iv + ah1[r];
                }
                __syncthreads();
#pragma unroll
                for (int p = 0; p < 2; ++p) {
                    int b = b0 + 32 * p;
                    float iv = zl[b * 33 + hc] + bias[0];
                    float fv = zl[b * 33 + 8 + hc] + bias[1];
                    float ov = zl[b * 33 + 16 + hc] + bias[2];
                    float gv = zl[b * 33 + 24 + hc] + bias[3];
                    float c = sigm_(fv) * c_own[p] + sigm_(iv) * tanh_(gv);
                    float h = sigm_(ov) * tanh_(c);
                    c_own[p] = c; h_own[p] = h;
                    st_wt_half(h2buf + (size_t)(tt & 1) * 65536 + (size_t)bk * 512 + b * 8 + hc, h);
                    float sm = h, sq = h * h;
                    sm += __shfl_xor(sm, 1); sm += __shfl_xor(sm, 2); sm += __shfl_xor(sm, 4);
                    sq += __shfl_xor(sq, 1); sq += __shfl_xor(sq, 2); sq += __shfl_xor(sq, 4);
                    if (hc == 0) {
                        atomicAdd(&s2[(size_t)(tt & 3) * 128 + b * 2 + 0], sm);
                        atomicAdd(&s2[(size_t)(tt & 3) * 128 + b * 2 + 1], sq);
                    }
                }
            } else if (do_out) {   // t == S_+1 tail: only the final out-LN row
                const float* sp = s2 + (size_t)((t - 2) & 3) * 128;
                ld_f32_sys(&o_sm0, sp + b0 * 2 + 0);
                ld_f32_sys(&o_sq0, sp + b0 * 2 + 1);
                ld_f32_sys(&o_sm1, sp + (b0 + 32) * 2 + 0);
                ld_f32_sys(&o_sq1, sp + (b0 + 32) * 2 + 1);
                TIE4FZ(o_sm0, o_sq0, o_sm1, o_sq1);
                int to = t - 2;
                float mean = o_sm0 * (1.f / 1024.f);
                float inv = rsqrtf(o_sq0 * (1.f / 1024.f) - mean * mean + 1e-5f);
                out[(size_t)b0 * (S_ * H_) + (size_t)to * H_ + col] =
                    (h_own[0] - mean) * inv * gl2v + bl2v;
                mean = o_sm1 * (1.f / 1024.f);
                inv = rsqrtf(o_sq1 * (1.f / 1024.f) - mean * mean + 1e-5f);
                out[(size_t)(b0 + 32) * (S_ * H_) + (size_t)to * H_ + col] =
                    (h_own[1] - mean) * inv * gl2v + bl2v;
            }
            if (tid == 0 && bk < 64) {
                st_wt_f32(&s2[(size_t)(t & 3) * 128 + bk * 2 + 0], 0.f);
                st_wt_f32(&s2[(size_t)(t & 3) * 128 + bk * 2 + 1], 0.f);
            }
        }

        // ---------------- grid barrier (two-level, fully relaxed, no cache ops) ----------------
        if (t <= S_) {
            wait_vm0();          // drain this wave's write-through stores/atomics to MALL
            __syncthreads();
            if (tid == 0) {
                int grp = bid & 7;
                unsigned old = __hip_atomic_fetch_add(&gsync[32 * (grp + 1)], 1u,
                                                      __ATOMIC_RELAXED, __HIP_MEMORY_SCOPE_AGENT);
                if (old == 32u * (unsigned)(t + 1) - 1u) {
                    __hip_atomic_fetch_add(&gsync[0], 1u, __ATOMIC_RELAXED, __HIP_MEMORY_SCOPE_AGENT);
                }
                unsigned tgt = 8u * (unsigned)(t + 1);
                while (__hip_atomic_load(&gsync[0], __ATOMIC_RELAXED, __HIP_MEMORY_SCOPE_AGENT) < tgt) {
                    __builtin_amdgcn_s_sleep(1);
                }
            }
            __syncthreads();
        }
    }

    // ---------------- finals ----------------
    const size_t BASE_H = (size_t)B_ * S_ * H_;
    const size_t BASE_C = BASE_H + (size_t)B_ * 2 * H_;
    int cc = is2 ? (1024 + col) : col;
#pragma unroll
    for (int p = 0; p < 2; ++p) {
        int b = b0 + 32 * p;
        out[BASE_H + (size_t)b * 2048 + cc] = h_own[p];
        out[BASE_C + (size_t)b * 2048 + cc] = c_own[p];
    }
}

// ---------------- host ----------------

extern "C" void kernel_launch(void* const* d_in, const int* in_sizes, int n_in,
                              void* d_out, int out_size, void* d_ws, size_t ws_size,
                              hipStream_t stream) {
    const int* src = (const int*)d_in[0];
    const float* emb = (const float*)d_in[1];
    const float* Wx1 = (const float*)d_in[2];
    const float* Wh1 = (const float*)d_in[3];
    const float* b1 = (const float*)d_in[4];
    const float* Wx2 = (const float*)d_in[5];
    const float* Wh2 = (const float*)d_in[6];
    const float* b2 = (const float*)d_in[7];
    const float* gl1 = (const float*)d_in[8];
    const float* bl1 = (const float*)d_in[9];
    const float* gl2 = (const float*)d_in[10];
    const float* bl2 = (const float*)d_in[11];
    float* out = (float*)d_out;
    char* ws = (char*)d_ws;
    if (ws_size < OFF_END) return;

    _Float16* img1 = (_Float16*)(ws + OFF_IMG1);
    _Float16* img2 = (_Float16*)(ws + OFF_IMG2);
    _Float16* x1seq = (_Float16*)(ws + OFF_X1);
    _Float16* h1buf = (_Float16*)(ws + OFF_H1);
    _Float16* h2buf = (_Float16*)(ws + OFF_H2);
    float* s1 = (float*)(ws + OFF_S1);
    float* s2 = (float*)(ws + OFF_S2);
    float* Gw = (float*)(ws + OFF_GW);
    float* B2e = (float*)(ws + OFF_B2E);
    unsigned int* gsync = (unsigned int*)(ws + OFF_SYNC);

    (void)hipFuncSetAttribute((const void*)k_rnn,
                              hipFuncAttributeMaxDynamicSharedMemorySize, LDS_TOTAL);

    unsigned zero_n = (unsigned)((OFF_END - OFF_H1) / 4);
    k_zero_ws<<<(zero_n + 255) / 256, 256, 0, stream>>>((float*)(ws + OFF_H1), zero_n);
    k_gather<<<8192, 256, 0, stream>>>(src, emb, x1seq);
    k_swz<<<7168, 256, 0, stream>>>(Wx1, Wh1, Wx2, Wh2, gl1, img1, img2);
    k_colsum<<<16, 256, 0, stream>>>(Wx2, gl1, bl1, b2, Gw, B2e);
    k_rnn<<<256, 256, LDS_TOTAL, stream>>>(b1, gl2, bl2, img1, img2, x1seq,
                                           h1buf, h2buf, s1, s2, Gw, B2e, gsync, out);
}